// Round 9
// baseline (280.964 us; speedup 1.0000x reference)
//
#include <hip/hip_runtime.h>
#include <math.h>

namespace {

constexpr int       kNME    = 262144;
constexpr int       kNDOF   = 524288;
constexpr long long kNNZ    = 16777216;   // kNME * 64
constexpr int       kNB     = 64;         // buckets
constexpr int       kBShift = 13;         // 8192 dofs / bucket
constexpr int       kBSpan  = 8192;
constexpr int       kEnt    = 4096;       // entries per producer block
constexpr int       kPerTh  = 16;         // kEnt / 256
constexpr int       kSortN  = kEnt + kNB * 4;   // sorted + per-run pad
constexpr int       kCtrStride = 16;      // counters padded to 64 B

constexpr float kEmin    = 1e-9f;
constexpr float kEmax    = 1.0f;
constexpr float kVolfrac = 0.4f;

using u32   = unsigned;
using i32x4 = __attribute__((ext_vector_type(4))) int;
using f32x4 = __attribute__((ext_vector_type(4))) float;
using u32x4 = __attribute__((ext_vector_type(4))) unsigned;

// pair = (localrow:13 bits << 19) | (fp32 bits >> 13)  [sign+exp+10 mantissa]
__device__ __forceinline__ u32 pack32(unsigned localrow, float v) {
    return (localrow << 19) | (__float_as_uint(v) >> 13);
}

// ---------------------------------------------------------------------------
// Kernel 1: per-element SIMP scale + rho partial sum.
// ---------------------------------------------------------------------------
__global__ void scale_kernel(const float* __restrict__ W_x,
                             float* __restrict__ scale,
                             float* __restrict__ rho_sum) {
    int i = blockIdx.x * blockDim.x + threadIdx.x;
    float rho = 0.0f;
    if (i < kNME) {
        float x = W_x[i];
        rho = 1.0f / (1.0f + __expf(-x));
        scale[i] = kEmin + rho * rho * rho * (kEmax - kEmin);
    }
    for (int off = 32; off > 0; off >>= 1) rho += __shfl_down(rho, off, 64);
    __shared__ float partial[4];
    const int lane = threadIdx.x & 63;
    const int wid  = threadIdx.x >> 6;
    if (lane == 0) partial[wid] = rho;
    __syncthreads();
    if (threadIdx.x == 0)
        atomicAdd(rho_sum, partial[0] + partial[1] + partial[2] + partial[3]);
}

// ---------------------------------------------------------------------------
// Producer: 4096-entry block (16/thread in two register halves).  Hist
// atomicAdd doubles as in-bucket rank.  Runs padded to 4 entries (pad slots
// pre-zeroed -> decode as +0.0 to dof 0), so copy-out is aligned dwordx4.
// rv[j]: bits[0:18] = row (19b), bits[19:30] = rank (12b).
// ---------------------------------------------------------------------------
__global__ __launch_bounds__(256, 6)
void producer_kernel(const float* __restrict__ K_sep,
                     const int*   __restrict__ rows,
                     const int*   __restrict__ cols,
                     const float* __restrict__ u,
                     const float* __restrict__ scale,
                     u32*         __restrict__ pairs,
                     unsigned*    __restrict__ counters,  // [kNB*R*kCtrStride]
                     long long chunk_base, unsigned capSub, int R) {
    __shared__ unsigned hist[kNB], ofs[kNB], gbase[kNB], h4s[kNB];
    __shared__ __align__(16) u32 sorted[kSortN];   // ~17 KB

    const int tid = threadIdx.x;
    const int sub = blockIdx.x & (R - 1);
    if (tid < kNB) hist[tid] = 0u;
    // Zero-fill sorted so run-pad slots decode as (row 0, +0.0).
    for (int i = tid; i < kSortN / 4; i += 256)
        ((u32x4*)sorted)[i] = u32x4{0u, 0u, 0u, 0u};
    __syncthreads();

    const long long i0 =
        chunk_base + (long long)blockIdx.x * kEnt + (long long)tid * kPerTh;
    const float s = scale[(int)(i0 >> 6)];   // all 16 share one element

    unsigned rv[kPerTh];
    float    vv[kPerTh];
    // Half A: entries 0..7
    {
        i32x4 r0 = __builtin_nontemporal_load((const i32x4*)(rows + i0));
        i32x4 r1 = __builtin_nontemporal_load((const i32x4*)(rows + i0) + 1);
        i32x4 c0 = __builtin_nontemporal_load((const i32x4*)(cols + i0));
        i32x4 c1 = __builtin_nontemporal_load((const i32x4*)(cols + i0) + 1);
        f32x4 k0 = __builtin_nontemporal_load((const f32x4*)(K_sep + i0));
        f32x4 k1 = __builtin_nontemporal_load((const f32x4*)(K_sep + i0) + 1);
#pragma unroll
        for (int j = 0; j < 4; ++j) {
            rv[j]     = (unsigned)r0[j];  vv[j]     = k0[j] * s * u[c0[j]];
            rv[j + 4] = (unsigned)r1[j];  vv[j + 4] = k1[j] * s * u[c1[j]];
        }
#pragma unroll
        for (int j = 0; j < 8; ++j)
            rv[j] |= atomicAdd(&hist[rv[j] >> kBShift], 1u) << 19;
    }
    // Half B: entries 8..15
    {
        const long long i8 = i0 + 8;
        i32x4 r0 = __builtin_nontemporal_load((const i32x4*)(rows + i8));
        i32x4 r1 = __builtin_nontemporal_load((const i32x4*)(rows + i8) + 1);
        i32x4 c0 = __builtin_nontemporal_load((const i32x4*)(cols + i8));
        i32x4 c1 = __builtin_nontemporal_load((const i32x4*)(cols + i8) + 1);
        f32x4 k0 = __builtin_nontemporal_load((const f32x4*)(K_sep + i8));
        f32x4 k1 = __builtin_nontemporal_load((const f32x4*)(K_sep + i8) + 1);
#pragma unroll
        for (int j = 0; j < 4; ++j) {
            rv[8 + j]  = (unsigned)r0[j];  vv[8 + j]  = k0[j] * s * u[c0[j]];
            rv[12 + j] = (unsigned)r1[j];  vv[12 + j] = k1[j] * s * u[c1[j]];
        }
#pragma unroll
        for (int j = 8; j < 16; ++j)
            rv[j] |= atomicAdd(&hist[rv[j] >> kBShift], 1u) << 19;
    }
    __syncthreads();

    // Wave 0: pad counts to 4, exclusive scan, reserve global sub-ranges.
    if (tid < kNB) {
        unsigned h  = hist[tid];
        unsigned h4 = (h + 3u) & ~3u;
        unsigned x  = h4;
#pragma unroll
        for (int off = 1; off < kNB; off <<= 1) {
            unsigned y = __shfl_up(x, off, 64);
            if (tid >= off) x += y;
        }
        ofs[tid]   = x - h4;            // 4-aligned run starts in LDS
        h4s[tid]   = h4;
        gbase[tid] = atomicAdd(&counters[(tid * R + sub) * kCtrStride], h4);
    }
    __syncthreads();

    // Scatter into sorted LDS order — no atomics (rank precomputed).
#pragma unroll
    for (int j = 0; j < kPerTh; ++j) {
        unsigned row = rv[j] & 0x7FFFFu;
        unsigned b   = row >> kBShift;
        unsigned pos = ofs[b] + (rv[j] >> 19);
        sorted[pos]  = pack32(row & (kBSpan - 1), vv[j]);
    }
    __syncthreads();

    // Coalesced copy-out: one wave per bucket run, aligned dwordx4 stores.
    const int wid = tid >> 6, lane = tid & 63;
    for (int b = wid; b < kNB; b += 4) {
        const unsigned s0 = ofs[b];
        const unsigned n4 = h4s[b];
        const unsigned g  = gbase[b];
        if (g >= capSub) continue;
        const unsigned m = min(n4, capSub - g);   // multiple of 4
        u32* dst = pairs + (size_t)(b * R + sub) * capSub + g;
        for (unsigned i = lane * 4; i < m; i += 256) {
            u32x4 w = *(const u32x4*)&sorted[s0 + i];
            __builtin_nontemporal_store(w, (u32x4*)(dst + i));
        }
    }
}

// ---------------------------------------------------------------------------
// Consumer: block (b, sub) owns one sub-region. 512 threads, 16B u32x4
// loads, fire-and-forget LDS atomics, private store of its partial tile.
// ---------------------------------------------------------------------------
__global__ __launch_bounds__(512, 8)
void consumer_kernel(const u32*      __restrict__ pairs,
                     const unsigned* __restrict__ counters,
                     float*          __restrict__ partial,
                     unsigned capSub, int R, int accum) {
    const int b   = blockIdx.x / R;
    const int sub = blockIdx.x - b * R;
    unsigned cnt = counters[(b * R + sub) * kCtrStride];
    if (cnt > capSub) cnt = capSub;

    __shared__ float acc[kBSpan];
    for (int i = threadIdx.x; i < kBSpan; i += 512) acc[i] = 0.0f;
    __syncthreads();

    const u32* p = pairs + (size_t)(b * R + sub) * capSub;
    const unsigned aligned = cnt & ~3u;           // cnt is a multiple of 4
    for (unsigned i = 4 * threadIdx.x; i < aligned; i += 4 * 512) {
        u32x4 e = __builtin_nontemporal_load((const u32x4*)(p + i));
#pragma unroll
        for (int j = 0; j < 4; ++j)
            atomicAdd(&acc[e[j] >> 19], __uint_as_float(e[j] << 13));
    }
    if (threadIdx.x < (cnt - aligned)) {
        u32 e = p[aligned + threadIdx.x];
        atomicAdd(&acc[e >> 19], __uint_as_float(e << 13));
    }
    __syncthreads();

    float* dst = partial + (size_t)(b * R + sub) * kBSpan;
    if (accum) {
        for (int i = threadIdx.x; i < kBSpan; i += 512) dst[i] += acc[i];
    } else {
        for (int i = threadIdx.x; i < kBSpan; i += 512) dst[i] = acc[i];
    }
}

// ---------------------------------------------------------------------------
// Norm: coalesced — block (b, chunk of 1024 dofs); vectorized sum over the
// R planes, then (Ku-f)^2 reduction.  Grid = kNB * (kBSpan/1024).
// ---------------------------------------------------------------------------
__global__ void norm_kernel(const float* __restrict__ partial,
                            const float* __restrict__ f,
                            float* __restrict__ norm_sum, int R) {
    const int b  = blockIdx.x >> 3;
    const int i0 = (blockIdx.x & 7) * 1024 + threadIdx.x * 4;
    f32x4 s = {0.0f, 0.0f, 0.0f, 0.0f};
    for (int r = 0; r < R; ++r)
        s += *(const f32x4*)(partial + (size_t)(b * R + r) * kBSpan + i0);
    f32x4 fv = *(const f32x4*)(f + (size_t)b * kBSpan + i0);
    f32x4 d  = s - fv;
    float a = d[0] * d[0] + d[1] * d[1] + d[2] * d[2] + d[3] * d[3];
    for (int off = 32; off > 0; off >>= 1) a += __shfl_down(a, off, 64);
    __shared__ float partial_s[4];
    const int lane = threadIdx.x & 63;
    const int wid  = threadIdx.x >> 6;
    if (lane == 0) partial_s[wid] = a;
    __syncthreads();
    if (threadIdx.x == 0)
        atomicAdd(norm_sum,
                  partial_s[0] + partial_s[1] + partial_s[2] + partial_s[3]);
}

// ---------------------------------------------------------------------------
// Fallback scatter (device atomics) if workspace is too small.
// ---------------------------------------------------------------------------
__global__ void scatter_dev_kernel(const float* __restrict__ K_sep,
                                   const int*   __restrict__ rows,
                                   const int*   __restrict__ cols,
                                   const float* __restrict__ u,
                                   const float* __restrict__ scale,
                                   float* __restrict__ Ku) {
    long long i = (long long)blockIdx.x * blockDim.x + threadIdx.x;
    if (i >= kNNZ) return;
    float s = scale[(int)(i >> 6)];
    atomicAdd(&Ku[rows[i]], K_sep[i] * s * u[cols[i]]);
}

__global__ void norm1_kernel(const float* __restrict__ Ku,
                             const float* __restrict__ f,
                             float* __restrict__ norm_sum) {
    float a = 0.0f;
    for (int i = blockIdx.x * blockDim.x + threadIdx.x; i < kNDOF;
         i += gridDim.x * blockDim.x) {
        float d = Ku[i] - f[i];
        a += d * d;
    }
    for (int off = 32; off > 0; off >>= 1) a += __shfl_down(a, off, 64);
    __shared__ float partial_s[4];
    const int lane = threadIdx.x & 63;
    const int wid  = threadIdx.x >> 6;
    if (lane == 0) partial_s[wid] = a;
    __syncthreads();
    if (threadIdx.x == 0)
        atomicAdd(norm_sum,
                  partial_s[0] + partial_s[1] + partial_s[2] + partial_s[3]);
}

__global__ void finalize_kernel(const float* __restrict__ acc,
                                float* __restrict__ out) {
    if (threadIdx.x == 0 && blockIdx.x == 0) {
        float rho_mean = acc[0] * (1.0f / (float)kNME);
        float vol = fmaxf(rho_mean - kVolfrac, 0.0f);
        out[0] = vol + sqrtf(acc[1]);
    }
}

}  // namespace

extern "C" void kernel_launch(void* const* d_in, const int* in_sizes, int n_in,
                              void* d_out, int out_size, void* d_ws, size_t ws_size,
                              hipStream_t stream) {
    const float* W_x   = (const float*)d_in[0];
    const float* K_sep = (const float*)d_in[1];
    const int*   idx   = (const int*)d_in[2];
    const float* u     = (const float*)d_in[3];
    const float* f     = (const float*)d_in[4];
    const int* rows = idx;
    const int* cols = idx + kNNZ;

    float* ws = (float*)d_ws;
    const size_t avail = ws_size / sizeof(float);

    // Pick (num_chunks, R, cap margin): first config that fits.
    // margin must cover count spread + run padding (<= 3 per block per bucket).
    struct Opt { int nc, R; unsigned margin; };
    const Opt opts[] = {{1, 16, 2048}, {1, 16, 1024}, {1, 8, 2048},
                        {2, 8, 2048},  {2, 8, 1024},  {4, 8, 1024},
                        {4, 4, 1024},  {8, 4, 1024}};
    int NC = -1, R = 16;
    unsigned capSub = 0;
    size_t ctrF = 0, partialF = 0;
    for (const Opt& o : opts) {
        long long perCell = kNNZ / ((long long)o.nc * kNB * o.R);
        unsigned  mc      = (unsigned)perCell + o.margin;   // multiple of 4
        size_t cf = (size_t)o.nc * kNB * o.R * kCtrStride;
        size_t pf = (size_t)kNB * o.R * kBSpan;
        size_t need = 16 + cf + pf + (size_t)kNME +
                      (size_t)kNB * o.R * (size_t)mc;       // pairs are u32
        if (need <= avail) {
            NC = o.nc; R = o.R; capSub = mc; ctrF = cf; partialF = pf;
            break;
        }
    }

    if (NC < 0) {
        // Fallback: device-atomic scatter (fits in ~3.2 MB).
        float* Ku    = ws;
        float* scale = ws + kNDOF;
        float* acc   = ws + kNDOF + kNME;
        hipMemsetAsync(ws, 0, (size_t)(kNDOF + kNME + 16) * sizeof(float), stream);
        scale_kernel<<<kNME / 256, 256, 0, stream>>>(W_x, scale, acc);
        scatter_dev_kernel<<<(int)(kNNZ / 256), 256, 0, stream>>>(
            K_sep, rows, cols, u, scale, Ku);
        norm1_kernel<<<2048, 256, 0, stream>>>(Ku, f, acc + 1);
        finalize_kernel<<<1, 64, 0, stream>>>(acc, (float*)d_out);
        return;
    }

    float*    acc      = ws;                          // [16]
    unsigned* counters = (unsigned*)(ws + 16);        // [NC][kNB*R*kCtrStride]
    float*    partial  = ws + 16 + ctrF;              // [kNB*R*kBSpan]
    float*    scale    = partial + partialF;          // [kNME]
    u32*      pairs    = (u32*)(scale + kNME);        // [kNB*R*capSub]

    // Zero acc + counters only (partial is stored, not accumulated, on c=0).
    hipMemsetAsync(ws, 0, (16 + ctrF) * sizeof(float), stream);

    scale_kernel<<<kNME / 256, 256, 0, stream>>>(W_x, scale, acc);

    const long long chunk = kNNZ / NC;
    const int prod_blocks = (int)(chunk / kEnt);
    for (int c = 0; c < NC; ++c) {
        unsigned* ctr = counters + (size_t)c * kNB * R * kCtrStride;
        producer_kernel<<<prod_blocks, 256, 0, stream>>>(
            K_sep, rows, cols, u, scale, pairs, ctr, chunk * c, capSub, R);
        consumer_kernel<<<kNB * R, 512, 0, stream>>>(
            pairs, ctr, partial, capSub, R, /*accum=*/c > 0 ? 1 : 0);
    }

    norm_kernel<<<kNB * (kBSpan / 1024), 256, 0, stream>>>(
        partial, f, acc + 1, R);

    finalize_kernel<<<1, 64, 0, stream>>>(acc, (float*)d_out);
}

// Round 10
// 270.307 us; speedup vs baseline: 1.0394x; 1.0394x over previous
//
#include <hip/hip_runtime.h>
#include <math.h>

namespace {

constexpr int       kNME    = 262144;
constexpr int       kNDOF   = 524288;
constexpr long long kNNZ    = 16777216;   // kNME * 64
constexpr int       kNB     = 64;         // buckets
constexpr int       kBShift = 13;         // 8192 dofs / bucket
constexpr int       kBSpan  = 8192;
constexpr int       kEnt    = 2048;       // entries per producer block
constexpr int       kPerTh  = 8;          // kEnt / 256
constexpr int       kSortN  = kEnt + kNB * 4;   // sorted + per-run pad
constexpr int       kCtrStride = 16;      // counters padded to 64 B

constexpr float kEmin    = 1e-9f;
constexpr float kEmax    = 1.0f;
constexpr float kVolfrac = 0.4f;

using u32   = unsigned;
using i32x4 = __attribute__((ext_vector_type(4))) int;
using f32x4 = __attribute__((ext_vector_type(4))) float;
using u32x4 = __attribute__((ext_vector_type(4))) unsigned;

// pair = (localrow:13 bits << 19) | (fp32 bits >> 13)  [sign+exp+10 mantissa]
__device__ __forceinline__ u32 pack32(unsigned localrow, float v) {
    return (localrow << 19) | (__float_as_uint(v) >> 13);
}

// ---------------------------------------------------------------------------
// Producer (scale fused): block covers 2048 entries = 32 consecutive W_x
// elements.  Inline sigmoid scale + block rho reduction.  Hist atomicAdd
// doubles as in-bucket rank; runs padded to 4; aligned dwordx4 copy-out.
// rv[j]: bits[0:18] = row (19b), bits[19:30] = rank (12b).
// ---------------------------------------------------------------------------
__global__ __launch_bounds__(256, 8)
void producer_kernel(const float* __restrict__ K_sep,
                     const int*   __restrict__ rows,
                     const int*   __restrict__ cols,
                     const float* __restrict__ u,
                     const float* __restrict__ W_x,
                     u32*         __restrict__ pairs,
                     unsigned*    __restrict__ counters,  // [kNB*R*kCtrStride]
                     float*       __restrict__ rho_sum,
                     long long chunk_base, unsigned capSub, int R) {
    __shared__ unsigned hist[kNB], ofs[kNB], gbase[kNB];
    __shared__ __align__(16) u32 sorted[kSortN];   // 9.2 KB
    __shared__ float rho_part[4];

    const int tid = threadIdx.x;
    const int sub = blockIdx.x & (R - 1);
    if (tid < kNB) hist[tid] = 0u;
    // Zero-fill sorted so run-pad slots decode as (row 0, +0.0).
    for (int i = tid; i < kSortN / 4; i += 256)
        ((u32x4*)sorted)[i] = u32x4{0u, 0u, 0u, 0u};
    __syncthreads();

    const long long i0 =
        chunk_base + (long long)blockIdx.x * kEnt + (long long)tid * kPerTh;

    // Fused SIMP scale: all 8 entries share one element (8 | 64).
    const float x   = W_x[(int)(i0 >> 6)];
    const float rho = 1.0f / (1.0f + __expf(-x));
    const float s   = kEmin + rho * rho * rho * (kEmax - kEmin);

    i32x4 r0 = __builtin_nontemporal_load((const i32x4*)(rows + i0));
    i32x4 r1 = __builtin_nontemporal_load((const i32x4*)(rows + i0) + 1);
    i32x4 c0 = __builtin_nontemporal_load((const i32x4*)(cols + i0));
    i32x4 c1 = __builtin_nontemporal_load((const i32x4*)(cols + i0) + 1);
    f32x4 k0 = __builtin_nontemporal_load((const f32x4*)(K_sep + i0));
    f32x4 k1 = __builtin_nontemporal_load((const f32x4*)(K_sep + i0) + 1);

    unsigned rv[kPerTh];
    float    vv[kPerTh];
#pragma unroll
    for (int j = 0; j < 4; ++j) {
        rv[j]     = (unsigned)r0[j];  vv[j]     = k0[j] * s * u[c0[j]];
        rv[j + 4] = (unsigned)r1[j];  vv[j + 4] = k1[j] * s * u[c1[j]];
    }
    // Histogram; returned old value IS this entry's rank in its bucket.
#pragma unroll
    for (int j = 0; j < kPerTh; ++j)
        rv[j] |= atomicAdd(&hist[rv[j] >> kBShift], 1u) << 19;

    // Block rho reduction (one contributor per element = every 8th thread).
    {
        float rt = ((tid & 7) == 0) ? rho : 0.0f;
        for (int off = 32; off > 0; off >>= 1) rt += __shfl_down(rt, off, 64);
        if ((tid & 63) == 0) rho_part[tid >> 6] = rt;
    }
    __syncthreads();
    if (tid == 0)
        atomicAdd(rho_sum,
                  rho_part[0] + rho_part[1] + rho_part[2] + rho_part[3]);

    // Wave 0: pad counts to 4, exclusive scan, reserve global sub-ranges.
    if (tid < kNB) {
        unsigned h4 = (hist[tid] + 3u) & ~3u;
        unsigned x4 = h4;
#pragma unroll
        for (int off = 1; off < kNB; off <<= 1) {
            unsigned y = __shfl_up(x4, off, 64);
            if (tid >= off) x4 += y;
        }
        ofs[tid]   = x4 - h4;           // 4-aligned run starts in LDS
        gbase[tid] = atomicAdd(&counters[(tid * R + sub) * kCtrStride], h4);
    }
    __syncthreads();

    // Scatter into sorted LDS order — no atomics (rank precomputed).
#pragma unroll
    for (int j = 0; j < kPerTh; ++j) {
        unsigned row = rv[j] & 0x7FFFFu;
        unsigned b   = row >> kBShift;
        unsigned pos = ofs[b] + (rv[j] >> 19);
        sorted[pos]  = pack32(row & (kBSpan - 1), vv[j]);
    }
    __syncthreads();

    // Coalesced copy-out: one wave per bucket run, aligned dwordx4 stores.
    const int wid = tid >> 6, lane = tid & 63;
    for (int b = wid; b < kNB; b += 4) {
        const unsigned s0 = ofs[b];
        const unsigned n4 = (hist[b] + 3u) & ~3u;
        const unsigned g  = gbase[b];
        if (g >= capSub) continue;
        const unsigned m = min(n4, capSub - g);   // multiple of 4
        u32* dst = pairs + (size_t)(b * R + sub) * capSub + g;
        for (unsigned i = lane * 4; i < m; i += 256) {
            u32x4 w = *(const u32x4*)&sorted[s0 + i];
            __builtin_nontemporal_store(w, (u32x4*)(dst + i));
        }
    }
}

// ---------------------------------------------------------------------------
// Consumer: block (b, sub) owns one sub-region. 512 threads, software-
// pipelined u32x4 loads -> LDS atomics, private store of its partial tile.
// ---------------------------------------------------------------------------
__global__ __launch_bounds__(512, 8)
void consumer_kernel(const u32*      __restrict__ pairs,
                     const unsigned* __restrict__ counters,
                     float*          __restrict__ partial,
                     unsigned capSub, int R, int accum) {
    const int b   = blockIdx.x / R;
    const int sub = blockIdx.x - b * R;
    unsigned cnt = counters[(b * R + sub) * kCtrStride];
    if (cnt > capSub) cnt = capSub;

    __shared__ float acc[kBSpan];
    for (int i = threadIdx.x; i < kBSpan; i += 512) acc[i] = 0.0f;
    __syncthreads();

    const u32* p = pairs + (size_t)(b * R + sub) * capSub;
    unsigned i = 4 * threadIdx.x;                 // cnt is a multiple of 4
    if (i < cnt) {
        u32x4 e = __builtin_nontemporal_load((const u32x4*)(p + i));
        for (i += 2048; i < cnt; i += 2048) {
            u32x4 n = __builtin_nontemporal_load((const u32x4*)(p + i));
#pragma unroll
            for (int j = 0; j < 4; ++j)
                atomicAdd(&acc[e[j] >> 19], __uint_as_float(e[j] << 13));
            e = n;
        }
#pragma unroll
        for (int j = 0; j < 4; ++j)
            atomicAdd(&acc[e[j] >> 19], __uint_as_float(e[j] << 13));
    }
    __syncthreads();

    float* dst = partial + (size_t)(b * R + sub) * kBSpan;
    if (accum) {
        for (int k = threadIdx.x; k < kBSpan; k += 512) dst[k] += acc[k];
    } else {
        for (int k = threadIdx.x; k < kBSpan; k += 512) dst[k] = acc[k];
    }
}

// ---------------------------------------------------------------------------
// Norm + finalize (fused via done-counter): block (b, chunk of 1024 dofs);
// vectorized sum over R planes; last finishing block writes the loss.
// Grid = kNB * (kBSpan/1024) = 512 blocks.
// acc layout: acc[0]=rho_sum, acc[1]=norm_sum, acc[2]=done counter (uint).
// ---------------------------------------------------------------------------
__global__ void norm_kernel(const float* __restrict__ partial,
                            const float* __restrict__ f,
                            float* __restrict__ acc,
                            float* __restrict__ out, int R) {
    const int b  = blockIdx.x >> 3;
    const int i0 = (blockIdx.x & 7) * 1024 + threadIdx.x * 4;
    f32x4 s = {0.0f, 0.0f, 0.0f, 0.0f};
    for (int r = 0; r < R; ++r)
        s += *(const f32x4*)(partial + (size_t)(b * R + r) * kBSpan + i0);
    f32x4 fv = *(const f32x4*)(f + (size_t)b * kBSpan + i0);
    f32x4 d  = s - fv;
    float a = d[0] * d[0] + d[1] * d[1] + d[2] * d[2] + d[3] * d[3];
    for (int off = 32; off > 0; off >>= 1) a += __shfl_down(a, off, 64);
    __shared__ float partial_s[4];
    const int lane = threadIdx.x & 63;
    const int wid  = threadIdx.x >> 6;
    if (lane == 0) partial_s[wid] = a;
    __syncthreads();
    if (threadIdx.x == 0) {
        atomicAdd(&acc[1],
                  partial_s[0] + partial_s[1] + partial_s[2] + partial_s[3]);
        __threadfence();
        unsigned done = atomicAdd((unsigned*)&acc[2], 1u);
        if (done == gridDim.x - 1) {
            float rs = __hip_atomic_load(&acc[0], __ATOMIC_RELAXED,
                                         __HIP_MEMORY_SCOPE_AGENT);
            float ns = __hip_atomic_load(&acc[1], __ATOMIC_RELAXED,
                                         __HIP_MEMORY_SCOPE_AGENT);
            float rho_mean = rs * (1.0f / (float)kNME);
            out[0] = fmaxf(rho_mean - kVolfrac, 0.0f) + sqrtf(ns);
        }
    }
}

// ---------------------------------------------------------------------------
// Fallback path (device atomics) if workspace is too small.
// ---------------------------------------------------------------------------
__global__ void scale_kernel(const float* __restrict__ W_x,
                             float* __restrict__ scale,
                             float* __restrict__ rho_sum) {
    int i = blockIdx.x * blockDim.x + threadIdx.x;
    float rho = 0.0f;
    if (i < kNME) {
        float x = W_x[i];
        rho = 1.0f / (1.0f + __expf(-x));
        scale[i] = kEmin + rho * rho * rho * (kEmax - kEmin);
    }
    for (int off = 32; off > 0; off >>= 1) rho += __shfl_down(rho, off, 64);
    __shared__ float partial[4];
    const int lane = threadIdx.x & 63;
    const int wid  = threadIdx.x >> 6;
    if (lane == 0) partial[wid] = rho;
    __syncthreads();
    if (threadIdx.x == 0)
        atomicAdd(rho_sum, partial[0] + partial[1] + partial[2] + partial[3]);
}

__global__ void scatter_dev_kernel(const float* __restrict__ K_sep,
                                   const int*   __restrict__ rows,
                                   const int*   __restrict__ cols,
                                   const float* __restrict__ u,
                                   const float* __restrict__ scale,
                                   float* __restrict__ Ku) {
    long long i = (long long)blockIdx.x * blockDim.x + threadIdx.x;
    if (i >= kNNZ) return;
    float s = scale[(int)(i >> 6)];
    atomicAdd(&Ku[rows[i]], K_sep[i] * s * u[cols[i]]);
}

__global__ void norm1_kernel(const float* __restrict__ Ku,
                             const float* __restrict__ f,
                             float* __restrict__ norm_sum) {
    float a = 0.0f;
    for (int i = blockIdx.x * blockDim.x + threadIdx.x; i < kNDOF;
         i += gridDim.x * blockDim.x) {
        float d = Ku[i] - f[i];
        a += d * d;
    }
    for (int off = 32; off > 0; off >>= 1) a += __shfl_down(a, off, 64);
    __shared__ float partial_s[4];
    const int lane = threadIdx.x & 63;
    const int wid  = threadIdx.x >> 6;
    if (lane == 0) partial_s[wid] = a;
    __syncthreads();
    if (threadIdx.x == 0)
        atomicAdd(norm_sum,
                  partial_s[0] + partial_s[1] + partial_s[2] + partial_s[3]);
}

__global__ void finalize_kernel(const float* __restrict__ acc,
                                float* __restrict__ out) {
    if (threadIdx.x == 0 && blockIdx.x == 0) {
        float rho_mean = acc[0] * (1.0f / (float)kNME);
        float vol = fmaxf(rho_mean - kVolfrac, 0.0f);
        out[0] = vol + sqrtf(acc[1]);
    }
}

}  // namespace

extern "C" void kernel_launch(void* const* d_in, const int* in_sizes, int n_in,
                              void* d_out, int out_size, void* d_ws, size_t ws_size,
                              hipStream_t stream) {
    const float* W_x   = (const float*)d_in[0];
    const float* K_sep = (const float*)d_in[1];
    const int*   idx   = (const int*)d_in[2];
    const float* u     = (const float*)d_in[3];
    const float* f     = (const float*)d_in[4];
    const int* rows = idx;
    const int* cols = idx + kNNZ;

    float* ws = (float*)d_ws;
    const size_t avail = ws_size / sizeof(float);

    // Pick (num_chunks, R, cap margin): first config that fits.
    // Margins keep capSub a multiple of 4 (aligned runs).
    struct Opt { int nc, R; unsigned margin; };
    const Opt opts[] = {{1, 16, 2048}, {1, 16, 1024}, {1, 8, 2048},
                        {2, 8, 2048},  {2, 8, 1024},  {4, 8, 1024},
                        {4, 4, 1024},  {8, 4, 1024}};
    int NC = -1, R = 16;
    unsigned capSub = 0;
    size_t ctrF = 0, partialF = 0;
    for (const Opt& o : opts) {
        long long perCell = kNNZ / ((long long)o.nc * kNB * o.R);
        unsigned  mc      = (unsigned)perCell + o.margin;   // multiple of 4
        size_t cf = (size_t)o.nc * kNB * o.R * kCtrStride;
        size_t pf = (size_t)kNB * o.R * kBSpan;
        size_t need = 16 + cf + pf + (size_t)kNB * o.R * (size_t)mc;
        if (need <= avail) {
            NC = o.nc; R = o.R; capSub = mc; ctrF = cf; partialF = pf;
            break;
        }
    }

    if (NC < 0) {
        // Fallback: device-atomic scatter (fits in ~3.2 MB).
        float* Ku    = ws;
        float* scale = ws + kNDOF;
        float* acc   = ws + kNDOF + kNME;
        hipMemsetAsync(ws, 0, (size_t)(kNDOF + kNME + 16) * sizeof(float), stream);
        scale_kernel<<<kNME / 256, 256, 0, stream>>>(W_x, scale, acc);
        scatter_dev_kernel<<<(int)(kNNZ / 256), 256, 0, stream>>>(
            K_sep, rows, cols, u, scale, Ku);
        norm1_kernel<<<2048, 256, 0, stream>>>(Ku, f, acc + 1);
        finalize_kernel<<<1, 64, 0, stream>>>(acc, (float*)d_out);
        return;
    }

    float*    acc      = ws;                          // [16] (rho, norm, done)
    unsigned* counters = (unsigned*)(ws + 16);        // [NC][kNB*R*kCtrStride]
    float*    partial  = ws + 16 + ctrF;              // [kNB*R*kBSpan]
    u32*      pairs    = (u32*)(partial + partialF);  // [kNB*R*capSub]

    // Zero acc + counters (partial is stored, not accumulated, on c=0).
    hipMemsetAsync(ws, 0, (16 + ctrF) * sizeof(float), stream);

    const long long chunk = kNNZ / NC;
    const int prod_blocks = (int)(chunk / kEnt);
    for (int c = 0; c < NC; ++c) {
        unsigned* ctr = counters + (size_t)c * kNB * R * kCtrStride;
        producer_kernel<<<prod_blocks, 256, 0, stream>>>(
            K_sep, rows, cols, u, W_x, pairs, ctr, acc, chunk * c, capSub, R);
        consumer_kernel<<<kNB * R, 512, 0, stream>>>(
            pairs, ctr, partial, capSub, R, /*accum=*/c > 0 ? 1 : 0);
    }

    norm_kernel<<<kNB * (kBSpan / 1024), 256, 0, stream>>>(
        partial, f, acc, (float*)d_out, R);
}